// Round 1
// baseline (8727.829 us; speedup 1.0000x reference)
//
#include <hip/hip_runtime.h>
#include <hip/hip_bf16.h>

// ---------------- degree / norm ----------------

__global__ __launch_bounds__(256) void deg_init_kernel(float* deg, int N) {
    int i = blockIdx.x * blockDim.x + threadIdx.x;
    if (i < N) deg[i] = 1.0f;  // self-loop
}

__global__ __launch_bounds__(256) void deg_count_kernel(const int* __restrict__ dst, float* deg, int E) {
    int i = blockIdx.x * blockDim.x + threadIdx.x;
    if (i < E) unsafeAtomicAdd(&deg[dst[i]], 1.0f);
}

__global__ __launch_bounds__(256) void deg_rsqrt_kernel(float* deg, int N) {
    int i = blockIdx.x * blockDim.x + threadIdx.x;
    if (i < N) deg[i] = rsqrtf(deg[i]);
}

// ---------------- GEMM: t[N][128] = f(h[N][128]) @ W[128][128] ----------------
// W held entirely in LDS (64 KB). 256 threads: tid&127 = col, tid>>7 = row-of-pair.
// If Wb != nullptr, W is the column-concatenation [Wa (128x64) | Wb (128x64)].
__global__ __launch_bounds__(256) void gemm128_kernel(const float* __restrict__ h,
                                                      const float* __restrict__ Wa,
                                                      const float* __restrict__ Wb,
                                                      float* __restrict__ t,
                                                      int N, int relu) {
    __shared__ float Wl[128 * 128];
    __shared__ float hl[2][128];

    for (int i = threadIdx.x; i < 128 * 128; i += 256) {
        int k = i >> 7, j = i & 127;
        float w;
        if (Wb) w = (j < 64) ? Wa[k * 64 + j] : Wb[k * 64 + (j - 64)];
        else    w = Wa[i];
        Wl[i] = w;
    }
    __syncthreads();

    int col = threadIdx.x & 127;
    int r   = threadIdx.x >> 7;

    for (long long pair = blockIdx.x; pair * 2 < N; pair += gridDim.x) {
        int row0 = (int)(pair * 2);
        {   // stage 2 rows: 256 threads -> 256 floats, coalesced
            int rr = threadIdx.x >> 7, k = threadIdx.x & 127;
            int row = row0 + rr;
            float v = (row < N) ? h[(size_t)row * 128 + k] : 0.0f;
            if (relu) v = fmaxf(v, 0.0f);
            hl[rr][k] = v;
        }
        __syncthreads();

        float acc = 0.0f;
        #pragma unroll
        for (int k = 0; k < 128; k += 4) {
            float4 hv = *(const float4*)&hl[r][k];
            acc += hv.x * Wl[(k + 0) * 128 + col];
            acc += hv.y * Wl[(k + 1) * 128 + col];
            acc += hv.z * Wl[(k + 2) * 128 + col];
            acc += hv.w * Wl[(k + 3) * 128 + col];
        }
        int row = row0 + r;
        if (row < N) t[(size_t)row * 128 + col] = acc;
        __syncthreads();
    }
}

// ---------------- self-loop init: out[v] = t[v]*dinv[v]^2 + b ----------------
__global__ __launch_bounds__(256) void init_self_kernel(const float4* __restrict__ t4,
                                                        const float* __restrict__ dinv,
                                                        const float* __restrict__ b,
                                                        float4* __restrict__ out,
                                                        int N) {
    int idx = blockIdx.x * blockDim.x + threadIdx.x;  // N*32
    int v = idx >> 5, c = idx & 31;
    if (v >= N) return;
    float di = dinv[v];
    float s = di * di;
    float4 x = t4[(size_t)v * 32 + c];
    float4 bb = ((const float4*)b)[c];
    out[(size_t)v * 32 + c] = make_float4(fmaf(x.x, s, bb.x), fmaf(x.y, s, bb.y),
                                          fmaf(x.z, s, bb.z), fmaf(x.w, s, bb.w));
}

// final layer: cols 0..63 -> mu (d_out[v*64+j]), cols 64..127 -> logstd (d_out[N*64 + v*64+j])
__global__ __launch_bounds__(256) void init_final_kernel(const float4* __restrict__ t4,
                                                         const float* __restrict__ dinv,
                                                         const float* __restrict__ bmu,
                                                         const float* __restrict__ bls,
                                                         float4* __restrict__ out4,
                                                         int N) {
    int idx = blockIdx.x * blockDim.x + threadIdx.x;  // N*32
    int v = idx >> 5, c = idx & 31;
    if (v >= N) return;
    int half = c >> 4, cc = c & 15;
    float di = dinv[v];
    float s = di * di;
    float4 x = t4[(size_t)v * 32 + c];
    float4 bb = half ? ((const float4*)bls)[cc] : ((const float4*)bmu)[cc];
    out4[(size_t)half * N * 16 + (size_t)v * 16 + cc] =
        make_float4(fmaf(x.x, s, bb.x), fmaf(x.y, s, bb.y),
                    fmaf(x.z, s, bb.z), fmaf(x.w, s, bb.w));
}

// ---------------- edge scatter: out[dst] += t[src] * dinv[src]*dinv[dst] ----------------
// 32 lanes per edge, float4 per lane.
__global__ __launch_bounds__(256) void agg_edge_kernel(const float4* __restrict__ t4,
                                                       const int* __restrict__ src,
                                                       const int* __restrict__ dst,
                                                       const float* __restrict__ dinv,
                                                       float* __restrict__ out,
                                                       int E) {
    int idx = blockIdx.x * blockDim.x + threadIdx.x;
    int e = idx >> 5, c = idx & 31;
    if (e >= E) return;
    int s = src[e], d = dst[e];
    float w = dinv[s] * dinv[d];
    float4 v = t4[(size_t)s * 32 + c];
    float* o = out + (size_t)d * 128 + c * 4;
    unsafeAtomicAdd(o + 0, v.x * w);
    unsafeAtomicAdd(o + 1, v.y * w);
    unsafeAtomicAdd(o + 2, v.z * w);
    unsafeAtomicAdd(o + 3, v.w * w);
}

__global__ __launch_bounds__(256) void agg_edge_final_kernel(const float4* __restrict__ t4,
                                                             const int* __restrict__ src,
                                                             const int* __restrict__ dst,
                                                             const float* __restrict__ dinv,
                                                             float* __restrict__ out,
                                                             int N, int E) {
    int idx = blockIdx.x * blockDim.x + threadIdx.x;
    int e = idx >> 5, c = idx & 31;
    if (e >= E) return;
    int s = src[e], d = dst[e];
    int half = c >> 4, cc = c & 15;
    float w = dinv[s] * dinv[d];
    float4 v = t4[(size_t)s * 32 + c];
    float* o = out + (size_t)half * N * 64 + (size_t)d * 64 + cc * 4;
    unsafeAtomicAdd(o + 0, v.x * w);
    unsafeAtomicAdd(o + 1, v.y * w);
    unsafeAtomicAdd(o + 2, v.z * w);
    unsafeAtomicAdd(o + 3, v.w * w);
}

// ---------------- launch ----------------

extern "C" void kernel_launch(void* const* d_in, const int* in_sizes, int n_in,
                              void* d_out, int out_size, void* d_ws, size_t ws_size,
                              hipStream_t stream) {
    const float* x   = (const float*)d_in[0];
    const int*   ei  = (const int*)d_in[1];
    const float* W1  = (const float*)d_in[2];
    const float* b1  = (const float*)d_in[3];
    const float* W2  = (const float*)d_in[4];
    const float* b2  = (const float*)d_in[5];
    const float* Wmu = (const float*)d_in[6];
    const float* bmu = (const float*)d_in[7];
    const float* Wls = (const float*)d_in[8];
    const float* bls = (const float*)d_in[9];

    const int N = in_sizes[0] / 128;
    const int E = in_sizes[1] / 2;
    const int* src = ei;
    const int* dst = ei + E;

    float* out = (float*)d_out;                 // also reused as h1/h2 buffer (N*128 floats)
    float* dinv = (float*)d_ws;
    size_t toff = ((size_t)N * sizeof(float) + 1023) & ~(size_t)1023;
    float* t = (float*)((char*)d_ws + toff);    // N*128 floats

    const int TB = 256;
    int gN    = (N + TB - 1) / TB;
    int gE    = (E + TB - 1) / TB;
    int gN32  = (N * 32 + TB - 1) / TB;
    int gE32h = (int)(((long long)E * 32 + TB - 1) / TB);
    int gGemm = 2048;

    // degrees -> dinv
    deg_init_kernel<<<gN, TB, 0, stream>>>(dinv, N);
    deg_count_kernel<<<gE, TB, 0, stream>>>(dst, dinv, E);
    deg_rsqrt_kernel<<<gN, TB, 0, stream>>>(dinv, N);

    // layer 1: t = x@W1 ; h1(out) = agg(t) + b1   (relu fused into next gemm)
    gemm128_kernel<<<gGemm, TB, 0, stream>>>(x, W1, nullptr, t, N, 0);
    init_self_kernel<<<gN32, TB, 0, stream>>>((const float4*)t, dinv, b1, (float4*)out, N);
    agg_edge_kernel<<<gE32h, TB, 0, stream>>>((const float4*)t, src, dst, dinv, out, E);

    // layer 2: t = relu(h1)@W2 ; h2(out) = agg(t) + b2
    gemm128_kernel<<<gGemm, TB, 0, stream>>>(out, W2, nullptr, t, N, 1);
    init_self_kernel<<<gN32, TB, 0, stream>>>((const float4*)t, dinv, b2, (float4*)out, N);
    agg_edge_kernel<<<gE32h, TB, 0, stream>>>((const float4*)t, src, dst, dinv, out, E);

    // layer 3+4 fused: t = relu(h2)@[Wmu|Wls] ; d_out = agg(t) + [bmu|bls] (split layout)
    gemm128_kernel<<<gGemm, TB, 0, stream>>>(out, Wmu, Wls, t, N, 1);
    init_final_kernel<<<gN32, TB, 0, stream>>>((const float4*)t, dinv, bmu, bls, (float4*)out, N);
    agg_edge_final_kernel<<<gE32h, TB, 0, stream>>>((const float4*)t, src, dst, dinv, out, N, E);
}

// Round 2
// 1091.028 us; speedup vs baseline: 7.9996x; 7.9996x over previous
//
#include <hip/hip_runtime.h>
#include <hip/hip_bf16.h>

// ---------------- small helpers ----------------
__device__ __forceinline__ float4 f4_fma(float4 a, float s, float4 acc) {
    acc.x = fmaf(a.x, s, acc.x); acc.y = fmaf(a.y, s, acc.y);
    acc.z = fmaf(a.z, s, acc.z); acc.w = fmaf(a.w, s, acc.w);
    return acc;
}
__device__ __forceinline__ float4 f4_add(float4 a, float4 b) {
    return make_float4(a.x + b.x, a.y + b.y, a.z + b.z, a.w + b.w);
}

// ---------------- degree / norm ----------------
__global__ __launch_bounds__(256) void cnt_count_kernel(const int* __restrict__ dst, int* cnt, int E) {
    int i = blockIdx.x * blockDim.x + threadIdx.x;
    if (i < E) atomicAdd(&cnt[dst[i]], 1);
}

__global__ __launch_bounds__(256) void dinv_kernel(const int* __restrict__ cnt, float* dinv, int N) {
    int i = blockIdx.x * blockDim.x + threadIdx.x;
    if (i < N) dinv[i] = rsqrtf((float)(cnt[i] + 1));  // +1 self-loop
}

// ---------------- exclusive scan (N ~ 100k) ----------------
#define SCAN_CHUNK 4096  // 256 threads * 16

__global__ __launch_bounds__(256) void scan_reduce_kernel(const int* __restrict__ cnt, int* bsum, int N) {
    __shared__ int sdata[256];
    int base = blockIdx.x * SCAN_CHUNK;
    int s = 0;
    for (int k = 0; k < 16; ++k) {
        int i = base + k * 256 + threadIdx.x;
        if (i < N) s += cnt[i];
    }
    sdata[threadIdx.x] = s;
    __syncthreads();
    for (int off = 128; off > 0; off >>= 1) {
        if (threadIdx.x < off) sdata[threadIdx.x] += sdata[threadIdx.x + off];
        __syncthreads();
    }
    if (threadIdx.x == 0) bsum[blockIdx.x] = sdata[0];
}

__global__ void scan_bsum_kernel(int* bsum, int B) {
    if (threadIdx.x == 0 && blockIdx.x == 0) {
        int run = 0;
        for (int i = 0; i < B; ++i) { int v = bsum[i]; bsum[i] = run; run += v; }
    }
}

__global__ __launch_bounds__(256) void scan_write_kernel(const int* __restrict__ cnt,
                                                         const int* __restrict__ bsum,
                                                         int* rowptr, int N) {
    __shared__ int sdata[256];
    int base = blockIdx.x * SCAN_CHUNK;
    int tbase = base + threadIdx.x * 16;
    int loc[16];
    int s = 0;
    for (int k = 0; k < 16; ++k) {
        int i = tbase + k;
        int v = (i < N) ? cnt[i] : 0;
        loc[k] = s; s += v;
    }
    sdata[threadIdx.x] = s;
    __syncthreads();
    for (int off = 1; off < 256; off <<= 1) {
        int v = sdata[threadIdx.x];
        int add = (threadIdx.x >= off) ? sdata[threadIdx.x - off] : 0;
        __syncthreads();
        sdata[threadIdx.x] = v + add;
        __syncthreads();
    }
    int texcl = (threadIdx.x == 0) ? 0 : sdata[threadIdx.x - 1];
    int boff = bsum[blockIdx.x];
    for (int k = 0; k < 16; ++k) {
        int i = tbase + k;
        if (i < N) rowptr[i] = boff + texcl + loc[k];
    }
}

__global__ __launch_bounds__(256) void cursor_init_kernel(const int* __restrict__ rowptr,
                                                          int* cursor, int* rowptr_end,
                                                          int N, int E) {
    int i = blockIdx.x * blockDim.x + threadIdx.x;
    if (i < N) cursor[i] = rowptr[i];
    if (i == N) *rowptr_end = E;  // rowptr[N] = E
}

__global__ __launch_bounds__(256) void csr_fill_kernel(const int* __restrict__ src,
                                                       const int* __restrict__ dst,
                                                       const float* __restrict__ dinv,
                                                       int* cursor, int* __restrict__ col,
                                                       float* __restrict__ ew, int E) {
    int e = blockIdx.x * blockDim.x + threadIdx.x;
    if (e >= E) return;
    int s = src[e], d = dst[e];
    int pos = atomicAdd(&cursor[d], 1);
    col[pos] = s;
    ew[pos] = dinv[s] * dinv[d];
}

// ---------------- GEMM: t[N][128] = f(h[N][128]) @ W[128][128] ----------------
__global__ __launch_bounds__(256) void gemm128_kernel(const float* __restrict__ h,
                                                      const float* __restrict__ Wa,
                                                      const float* __restrict__ Wb,
                                                      float* __restrict__ t,
                                                      int N, int relu) {
    __shared__ float Wl[128 * 128];
    __shared__ float hl[2][128];

    for (int i = threadIdx.x; i < 128 * 128; i += 256) {
        int k = i >> 7, j = i & 127;
        float w;
        if (Wb) w = (j < 64) ? Wa[k * 64 + j] : Wb[k * 64 + (j - 64)];
        else    w = Wa[i];
        Wl[i] = w;
    }
    __syncthreads();

    int col = threadIdx.x & 127;
    int r   = threadIdx.x >> 7;

    for (long long pair = blockIdx.x; pair * 2 < N; pair += gridDim.x) {
        int row0 = (int)(pair * 2);
        {
            int rr = threadIdx.x >> 7, k = threadIdx.x & 127;
            int row = row0 + rr;
            float v = (row < N) ? h[(size_t)row * 128 + k] : 0.0f;
            if (relu) v = fmaxf(v, 0.0f);
            hl[rr][k] = v;
        }
        __syncthreads();

        float acc = 0.0f;
        #pragma unroll
        for (int k = 0; k < 128; k += 4) {
            float4 hv = *(const float4*)&hl[r][k];
            acc += hv.x * Wl[(k + 0) * 128 + col];
            acc += hv.y * Wl[(k + 1) * 128 + col];
            acc += hv.z * Wl[(k + 2) * 128 + col];
            acc += hv.w * Wl[(k + 3) * 128 + col];
        }
        int row = row0 + r;
        if (row < N) t[(size_t)row * 128 + col] = acc;
        __syncthreads();
    }
}

// ---------------- pull aggregation: out[v] = sum_{e in in(v)} t[col[e]]*ew[e] + t[v]*dinv[v]^2 + b ----------------
__global__ __launch_bounds__(256) void agg_pull_kernel(const float4* __restrict__ t4,
                                                       const int* __restrict__ rowptr,
                                                       const int* __restrict__ col,
                                                       const float* __restrict__ ew,
                                                       const float* __restrict__ dinv,
                                                       const float* __restrict__ b,
                                                       float4* __restrict__ out4,
                                                       int N) {
    int v = blockIdx.x * 8 + (threadIdx.x >> 5);
    int c = threadIdx.x & 31;
    if (v >= N) return;
    int beg = rowptr[v], end = rowptr[v + 1];
    float di = dinv[v];
    float4 acc0 = f4_fma(t4[(size_t)v * 32 + c], di * di, ((const float4*)b)[c]);
    float4 acc1 = make_float4(0.f, 0.f, 0.f, 0.f);
    int e = beg;
    for (; e + 1 < end; e += 2) {
        int s0 = col[e], s1 = col[e + 1];
        float w0 = ew[e], w1 = ew[e + 1];
        float4 a = t4[(size_t)s0 * 32 + c];
        float4 bb = t4[(size_t)s1 * 32 + c];
        acc0 = f4_fma(a, w0, acc0);
        acc1 = f4_fma(bb, w1, acc1);
    }
    if (e < end) acc0 = f4_fma(t4[(size_t)col[e] * 32 + c], ew[e], acc0);
    out4[(size_t)v * 32 + c] = f4_add(acc0, acc1);
}

// final layer: cols 0..63 -> mu, 64..127 -> logstd (split output)
__global__ __launch_bounds__(256) void agg_pull_final_kernel(const float4* __restrict__ t4,
                                                             const int* __restrict__ rowptr,
                                                             const int* __restrict__ col,
                                                             const float* __restrict__ ew,
                                                             const float* __restrict__ dinv,
                                                             const float* __restrict__ bmu,
                                                             const float* __restrict__ bls,
                                                             float4* __restrict__ out4,
                                                             int N) {
    int v = blockIdx.x * 8 + (threadIdx.x >> 5);
    int c = threadIdx.x & 31;
    if (v >= N) return;
    int half = c >> 4, cc = c & 15;
    int beg = rowptr[v], end = rowptr[v + 1];
    float di = dinv[v];
    float4 bb = half ? ((const float4*)bls)[cc] : ((const float4*)bmu)[cc];
    float4 acc0 = f4_fma(t4[(size_t)v * 32 + c], di * di, bb);
    float4 acc1 = make_float4(0.f, 0.f, 0.f, 0.f);
    int e = beg;
    for (; e + 1 < end; e += 2) {
        int s0 = col[e], s1 = col[e + 1];
        float w0 = ew[e], w1 = ew[e + 1];
        float4 a = t4[(size_t)s0 * 32 + c];
        float4 b2 = t4[(size_t)s1 * 32 + c];
        acc0 = f4_fma(a, w0, acc0);
        acc1 = f4_fma(b2, w1, acc1);
    }
    if (e < end) acc0 = f4_fma(t4[(size_t)col[e] * 32 + c], ew[e], acc0);
    out4[(size_t)half * N * 16 + (size_t)v * 16 + cc] = f4_add(acc0, acc1);
}

// ---------------- fallback (atomic scatter) kernels ----------------
__global__ __launch_bounds__(256) void deg_init_kernel(float* deg, int N) {
    int i = blockIdx.x * blockDim.x + threadIdx.x;
    if (i < N) deg[i] = 1.0f;
}
__global__ __launch_bounds__(256) void deg_count_kernel(const int* __restrict__ dst, float* deg, int E) {
    int i = blockIdx.x * blockDim.x + threadIdx.x;
    if (i < E) unsafeAtomicAdd(&deg[dst[i]], 1.0f);
}
__global__ __launch_bounds__(256) void deg_rsqrt_kernel(float* deg, int N) {
    int i = blockIdx.x * blockDim.x + threadIdx.x;
    if (i < N) deg[i] = rsqrtf(deg[i]);
}
__global__ __launch_bounds__(256) void init_self_kernel(const float4* __restrict__ t4,
                                                        const float* __restrict__ dinv,
                                                        const float* __restrict__ b,
                                                        float4* __restrict__ out, int N) {
    int idx = blockIdx.x * blockDim.x + threadIdx.x;
    int v = idx >> 5, c = idx & 31;
    if (v >= N) return;
    float di = dinv[v];
    float s = di * di;
    float4 x = t4[(size_t)v * 32 + c];
    float4 bb = ((const float4*)b)[c];
    out[(size_t)v * 32 + c] = make_float4(fmaf(x.x, s, bb.x), fmaf(x.y, s, bb.y),
                                          fmaf(x.z, s, bb.z), fmaf(x.w, s, bb.w));
}
__global__ __launch_bounds__(256) void init_final_kernel(const float4* __restrict__ t4,
                                                         const float* __restrict__ dinv,
                                                         const float* __restrict__ bmu,
                                                         const float* __restrict__ bls,
                                                         float4* __restrict__ out4, int N) {
    int idx = blockIdx.x * blockDim.x + threadIdx.x;
    int v = idx >> 5, c = idx & 31;
    if (v >= N) return;
    int half = c >> 4, cc = c & 15;
    float di = dinv[v];
    float s = di * di;
    float4 x = t4[(size_t)v * 32 + c];
    float4 bb = half ? ((const float4*)bls)[cc] : ((const float4*)bmu)[cc];
    out4[(size_t)half * N * 16 + (size_t)v * 16 + cc] =
        make_float4(fmaf(x.x, s, bb.x), fmaf(x.y, s, bb.y),
                    fmaf(x.z, s, bb.z), fmaf(x.w, s, bb.w));
}
__global__ __launch_bounds__(256) void agg_edge_kernel(const float4* __restrict__ t4,
                                                       const int* __restrict__ src,
                                                       const int* __restrict__ dst,
                                                       const float* __restrict__ dinv,
                                                       float* __restrict__ out, int E) {
    int idx = blockIdx.x * blockDim.x + threadIdx.x;
    int e = idx >> 5, c = idx & 31;
    if (e >= E) return;
    int s = src[e], d = dst[e];
    float w = dinv[s] * dinv[d];
    float4 v = t4[(size_t)s * 32 + c];
    float* o = out + (size_t)d * 128 + c * 4;
    unsafeAtomicAdd(o + 0, v.x * w);
    unsafeAtomicAdd(o + 1, v.y * w);
    unsafeAtomicAdd(o + 2, v.z * w);
    unsafeAtomicAdd(o + 3, v.w * w);
}
__global__ __launch_bounds__(256) void agg_edge_final_kernel(const float4* __restrict__ t4,
                                                             const int* __restrict__ src,
                                                             const int* __restrict__ dst,
                                                             const float* __restrict__ dinv,
                                                             float* __restrict__ out, int N, int E) {
    int idx = blockIdx.x * blockDim.x + threadIdx.x;
    int e = idx >> 5, c = idx & 31;
    if (e >= E) return;
    int s = src[e], d = dst[e];
    int half = c >> 4, cc = c & 15;
    float w = dinv[s] * dinv[d];
    float4 v = t4[(size_t)s * 32 + c];
    float* o = out + (size_t)half * N * 64 + (size_t)d * 64 + cc * 4;
    unsafeAtomicAdd(o + 0, v.x * w);
    unsafeAtomicAdd(o + 1, v.y * w);
    unsafeAtomicAdd(o + 2, v.z * w);
    unsafeAtomicAdd(o + 3, v.w * w);
}

// ---------------- launch ----------------
extern "C" void kernel_launch(void* const* d_in, const int* in_sizes, int n_in,
                              void* d_out, int out_size, void* d_ws, size_t ws_size,
                              hipStream_t stream) {
    const float* x   = (const float*)d_in[0];
    const int*   ei  = (const int*)d_in[1];
    const float* W1  = (const float*)d_in[2];
    const float* b1  = (const float*)d_in[3];
    const float* W2  = (const float*)d_in[4];
    const float* b2  = (const float*)d_in[5];
    const float* Wmu = (const float*)d_in[6];
    const float* bmu = (const float*)d_in[7];
    const float* Wls = (const float*)d_in[8];
    const float* bls = (const float*)d_in[9];

    const int N = in_sizes[0] / 128;
    const int E = in_sizes[1] / 2;
    const int* src = ei;
    const int* dst = ei + E;

    float* out = (float*)d_out;  // reused as h1/h2 buffer

    auto align256 = [](size_t o) { return (o + 255) & ~(size_t)255; };
    const int B1 = (N + SCAN_CHUNK - 1) / SCAN_CHUNK;

    size_t off = 0;
    size_t o_dinv   = off; off = align256(off + (size_t)N * 4);
    size_t o_t      = off; off = align256(off + (size_t)N * 128 * 4);
    size_t o_rowptr = off; off = align256(off + (size_t)(N + 1) * 4);
    size_t o_cursor = off; off = align256(off + (size_t)N * 4);       // also cnt
    size_t o_bsum   = off; off = align256(off + (size_t)B1 * 4);
    size_t o_col    = off; off = align256(off + (size_t)E * 4);
    size_t o_ew     = off; off = align256(off + (size_t)E * 4);
    size_t need = off;

    float* dinv = (float*)((char*)d_ws + o_dinv);
    float* t    = (float*)((char*)d_ws + o_t);

    const int TB = 256;
    int gN    = (N + TB - 1) / TB;
    int gE    = (E + TB - 1) / TB;
    int gGemm = 2048;

    if (ws_size >= need) {
        int* rowptr = (int*)((char*)d_ws + o_rowptr);
        int* cursor = (int*)((char*)d_ws + o_cursor);  // doubles as cnt
        int* bsum   = (int*)((char*)d_ws + o_bsum);
        int* col    = (int*)((char*)d_ws + o_col);
        float* ew   = (float*)((char*)d_ws + o_ew);

        // CSR build
        hipMemsetAsync(cursor, 0, (size_t)N * 4, stream);
        cnt_count_kernel<<<gE, TB, 0, stream>>>(dst, cursor, E);
        dinv_kernel<<<gN, TB, 0, stream>>>(cursor, dinv, N);
        scan_reduce_kernel<<<B1, TB, 0, stream>>>(cursor, bsum, N);
        scan_bsum_kernel<<<1, 64, 0, stream>>>(bsum, B1);
        scan_write_kernel<<<B1, TB, 0, stream>>>(cursor, bsum, rowptr, N);
        cursor_init_kernel<<<(N + TB) / TB, TB, 0, stream>>>(rowptr, cursor, rowptr + N, N, E);
        csr_fill_kernel<<<gE, TB, 0, stream>>>(src, dst, dinv, cursor, col, ew, E);

        int gPull = (N + 7) / 8;
        // layer 1
        gemm128_kernel<<<gGemm, TB, 0, stream>>>(x, W1, nullptr, t, N, 0);
        agg_pull_kernel<<<gPull, TB, 0, stream>>>((const float4*)t, rowptr, col, ew, dinv, b1, (float4*)out, N);
        // layer 2
        gemm128_kernel<<<gGemm, TB, 0, stream>>>(out, W2, nullptr, t, N, 1);
        agg_pull_kernel<<<gPull, TB, 0, stream>>>((const float4*)t, rowptr, col, ew, dinv, b2, (float4*)out, N);
        // layer 3+4 fused
        gemm128_kernel<<<gGemm, TB, 0, stream>>>(out, Wmu, Wls, t, N, 1);
        agg_pull_final_kernel<<<gPull, TB, 0, stream>>>((const float4*)t, rowptr, col, ew, dinv, bmu, bls, (float4*)out, N);
    } else {
        // fallback: atomic scatter path
        int gN32  = (N * 32 + TB - 1) / TB;
        int gE32h = (int)(((long long)E * 32 + TB - 1) / TB);
        deg_init_kernel<<<gN, TB, 0, stream>>>(dinv, N);
        deg_count_kernel<<<gE, TB, 0, stream>>>(dst, dinv, E);
        deg_rsqrt_kernel<<<gN, TB, 0, stream>>>(dinv, N);

        gemm128_kernel<<<gGemm, TB, 0, stream>>>(x, W1, nullptr, t, N, 0);
        init_self_kernel<<<gN32, TB, 0, stream>>>((const float4*)t, dinv, b1, (float4*)out, N);
        agg_edge_kernel<<<gE32h, TB, 0, stream>>>((const float4*)t, src, dst, dinv, out, E);

        gemm128_kernel<<<gGemm, TB, 0, stream>>>(out, W2, nullptr, t, N, 1);
        init_self_kernel<<<gN32, TB, 0, stream>>>((const float4*)t, dinv, b2, (float4*)out, N);
        agg_edge_kernel<<<gE32h, TB, 0, stream>>>((const float4*)t, src, dst, dinv, out, E);

        gemm128_kernel<<<gGemm, TB, 0, stream>>>(out, Wmu, Wls, t, N, 1);
        init_final_kernel<<<gN32, TB, 0, stream>>>((const float4*)t, dinv, bmu, bls, (float4*)out, N);
        agg_edge_final_kernel<<<gE32h, TB, 0, stream>>>((const float4*)t, src, dst, dinv, out, N, E);
    }
}

// Round 3
// 778.934 us; speedup vs baseline: 11.2048x; 1.4007x over previous
//
#include <hip/hip_runtime.h>
#include <hip/hip_bf16.h>

// ---------------- small helpers ----------------
__device__ __forceinline__ float4 f4_fma(float4 a, float s, float4 acc) {
    acc.x = fmaf(a.x, s, acc.x); acc.y = fmaf(a.y, s, acc.y);
    acc.z = fmaf(a.z, s, acc.z); acc.w = fmaf(a.w, s, acc.w);
    return acc;
}
__device__ __forceinline__ float4 f4_add(float4 a, float4 b) {
    return make_float4(a.x + b.x, a.y + b.y, a.z + b.z, a.w + b.w);
}

typedef const __attribute__((address_space(1))) unsigned int* gas_u32;
typedef __attribute__((address_space(3))) unsigned int* las_u32;

__device__ __forceinline__ void gl_lds16(const float* g, float* l) {
    __builtin_amdgcn_global_load_lds((gas_u32)(const void*)g, (las_u32)(void*)l, 16, 0, 0);
}

// ---------------- degree / norm ----------------
__global__ __launch_bounds__(256) void cnt_count_kernel(const int* __restrict__ dst, int* cnt, int E) {
    int i = blockIdx.x * blockDim.x + threadIdx.x;
    if (i < E) atomicAdd(&cnt[dst[i]], 1);
}

__global__ __launch_bounds__(256) void dinv_kernel(const int* __restrict__ cnt, float* dinv, int N) {
    int i = blockIdx.x * blockDim.x + threadIdx.x;
    if (i < N) dinv[i] = rsqrtf((float)(cnt[i] + 1));  // +1 self-loop
}

// ---------------- exclusive scan (N ~ 100k) ----------------
#define SCAN_CHUNK 4096  // 256 threads * 16

__global__ __launch_bounds__(256) void scan_reduce_kernel(const int* __restrict__ cnt, int* bsum, int N) {
    __shared__ int sdata[256];
    int base = blockIdx.x * SCAN_CHUNK;
    int s = 0;
    for (int k = 0; k < 16; ++k) {
        int i = base + k * 256 + threadIdx.x;
        if (i < N) s += cnt[i];
    }
    sdata[threadIdx.x] = s;
    __syncthreads();
    for (int off = 128; off > 0; off >>= 1) {
        if (threadIdx.x < off) sdata[threadIdx.x] += sdata[threadIdx.x + off];
        __syncthreads();
    }
    if (threadIdx.x == 0) bsum[blockIdx.x] = sdata[0];
}

__global__ void scan_bsum_kernel(int* bsum, int B) {
    if (threadIdx.x == 0 && blockIdx.x == 0) {
        int run = 0;
        for (int i = 0; i < B; ++i) { int v = bsum[i]; bsum[i] = run; run += v; }
    }
}

__global__ __launch_bounds__(256) void scan_write_kernel(const int* __restrict__ cnt,
                                                         const int* __restrict__ bsum,
                                                         int* rowptr, int N) {
    __shared__ int sdata[256];
    int base = blockIdx.x * SCAN_CHUNK;
    int tbase = base + threadIdx.x * 16;
    int loc[16];
    int s = 0;
    for (int k = 0; k < 16; ++k) {
        int i = tbase + k;
        int v = (i < N) ? cnt[i] : 0;
        loc[k] = s; s += v;
    }
    sdata[threadIdx.x] = s;
    __syncthreads();
    for (int off = 1; off < 256; off <<= 1) {
        int v = sdata[threadIdx.x];
        int add = (threadIdx.x >= off) ? sdata[threadIdx.x - off] : 0;
        __syncthreads();
        sdata[threadIdx.x] = v + add;
        __syncthreads();
    }
    int texcl = (threadIdx.x == 0) ? 0 : sdata[threadIdx.x - 1];
    int boff = bsum[blockIdx.x];
    for (int k = 0; k < 16; ++k) {
        int i = tbase + k;
        if (i < N) rowptr[i] = boff + texcl + loc[k];
    }
}

__global__ __launch_bounds__(256) void cursor_init_kernel(const int* __restrict__ rowptr,
                                                          int* cursor, int* rowptr_end,
                                                          int N, int E) {
    int i = blockIdx.x * blockDim.x + threadIdx.x;
    if (i < N) cursor[i] = rowptr[i];
    if (i == N) *rowptr_end = E;  // rowptr[N] = E
}

__global__ __launch_bounds__(256) void csr_fill_kernel(const int* __restrict__ src,
                                                       const int* __restrict__ dst,
                                                       const float* __restrict__ dinv,
                                                       int* cursor, int* __restrict__ col,
                                                       float* __restrict__ ew, int E) {
    int e = blockIdx.x * blockDim.x + threadIdx.x;
    if (e >= E) return;
    int s = src[e], d = dst[e];
    int pos = atomicAdd(&cursor[d], 1);
    col[pos] = s;
    ew[pos] = dinv[s] * dinv[d];
}

// ---------------- register-tiled GEMM: t[N][128] = h[N][128] @ W[128][128] ----------------
// 256 threads, tile = 64 rows x 128 cols. Thread: 8 rows x 4 cols acc.
// W fully in LDS (64 KB); h tile double-buffered (2x32 KB) via global_load_lds.
#define TILE_R 64

__global__ __launch_bounds__(256) void gemm128_tiled(const float* __restrict__ h,
                                                     const float* __restrict__ Wa,
                                                     const float* __restrict__ Wb,
                                                     float* __restrict__ t,
                                                     int N, int ntiles) {
    __shared__ float Wl[128 * 128];
    __shared__ float hl[2][TILE_R * 128];

    // stage W (once per block)
    for (int i = threadIdx.x; i < 128 * 128; i += 256) {
        int k = i >> 7, j = i & 127;
        float w = Wb ? ((j < 64) ? Wa[k * 64 + j] : Wb[k * 64 + (j - 64)]) : Wa[i];
        Wl[i] = w;
    }

    const int lane = threadIdx.x & 63;
    const int wav  = threadIdx.x >> 6;   // 0..3
    const int jf4  = threadIdx.x & 31;   // float4 col index (cols jf4*4..+3)
    const int rg   = threadIdx.x >> 5;   // 0..7 (rows rg*8..rg*8+7)

    auto stage = [&](int buf, long long tile) {
        if (tile >= ntiles) return;
        long long row0 = tile * TILE_R;
        if (row0 + TILE_R <= N) {
            // fast path: async global->LDS, contiguous per wave (2 rows / 1024B per instr)
            const float* gbase = h + row0 * 128 + (size_t)wav * (16 * 128) + lane * 4;
            float* lbase = &hl[buf][wav * (16 * 128)];
            #pragma unroll
            for (int m = 0; m < 8; ++m)
                gl_lds16(gbase + m * 256, lbase + m * 256);
        } else {
            // guarded tail path (register staging, zero-fill)
            for (int i = threadIdx.x; i < TILE_R * 32; i += 256) {
                int rl = i >> 5, k4 = i & 31;
                long long row = row0 + rl;
                float4 v = (row < N) ? ((const float4*)h)[row * 32 + k4]
                                     : make_float4(0.f, 0.f, 0.f, 0.f);
                *(float4*)&hl[buf][rl * 128 + k4 * 4] = v;
            }
        }
    };

    long long tile = blockIdx.x;
    stage(0, tile);
    __syncthreads();
    int cur = 0;

    for (; tile < ntiles; tile += gridDim.x) {
        stage(cur ^ 1, tile + gridDim.x);  // prefetch next tile into other buffer

        float4 acc[8];
        #pragma unroll
        for (int rr = 0; rr < 8; ++rr) acc[rr] = make_float4(0.f, 0.f, 0.f, 0.f);

        const float* hb = &hl[cur][rg * 8 * 128];
        #pragma unroll 4
        for (int k = 0; k < 128; k += 4) {
            float4 w0 = *(const float4*)&Wl[(k + 0) * 128 + jf4 * 4];
            float4 w1 = *(const float4*)&Wl[(k + 1) * 128 + jf4 * 4];
            float4 w2 = *(const float4*)&Wl[(k + 2) * 128 + jf4 * 4];
            float4 w3 = *(const float4*)&Wl[(k + 3) * 128 + jf4 * 4];
            #pragma unroll
            for (int rr = 0; rr < 8; ++rr) {
                float4 hv = *(const float4*)&hb[rr * 128 + k];
                acc[rr] = f4_fma(w0, hv.x, acc[rr]);
                acc[rr] = f4_fma(w1, hv.y, acc[rr]);
                acc[rr] = f4_fma(w2, hv.z, acc[rr]);
                acc[rr] = f4_fma(w3, hv.w, acc[rr]);
            }
        }

        long long row0 = tile * TILE_R;
        #pragma unroll
        for (int rr = 0; rr < 8; ++rr) {
            long long row = row0 + rg * 8 + rr;
            if (row < N) ((float4*)t)[row * 32 + jf4] = acc[rr];
        }
        __syncthreads();
        cur ^= 1;
    }
}

// ---------------- pull aggregation ----------------
// out[v] = sum_in t[col[e]]*ew[e] + t[v]*dinv[v]^2 + b ; optional relu for hidden layers
__global__ __launch_bounds__(256) void agg_pull_kernel(const float4* __restrict__ t4,
                                                       const int* __restrict__ rowptr,
                                                       const int* __restrict__ col,
                                                       const float* __restrict__ ew,
                                                       const float* __restrict__ dinv,
                                                       const float* __restrict__ b,
                                                       float4* __restrict__ out4,
                                                       int N, int relu) {
    int v = blockIdx.x * 8 + (threadIdx.x >> 5);
    int c = threadIdx.x & 31;
    if (v >= N) return;
    int beg = rowptr[v], end = rowptr[v + 1];
    float di = dinv[v];
    float4 acc0 = f4_fma(t4[(size_t)v * 32 + c], di * di, ((const float4*)b)[c]);
    float4 acc1 = make_float4(0.f, 0.f, 0.f, 0.f);
    int e = beg;
    for (; e + 1 < end; e += 2) {
        int s0 = col[e], s1 = col[e + 1];
        float w0 = ew[e], w1 = ew[e + 1];
        float4 a = t4[(size_t)s0 * 32 + c];
        float4 bb = t4[(size_t)s1 * 32 + c];
        acc0 = f4_fma(a, w0, acc0);
        acc1 = f4_fma(bb, w1, acc1);
    }
    if (e < end) acc0 = f4_fma(t4[(size_t)col[e] * 32 + c], ew[e], acc0);
    float4 r = f4_add(acc0, acc1);
    if (relu) {
        r.x = fmaxf(r.x, 0.f); r.y = fmaxf(r.y, 0.f);
        r.z = fmaxf(r.z, 0.f); r.w = fmaxf(r.w, 0.f);
    }
    out4[(size_t)v * 32 + c] = r;
}

// final layer: cols 0..63 -> mu, 64..127 -> logstd (split output)
__global__ __launch_bounds__(256) void agg_pull_final_kernel(const float4* __restrict__ t4,
                                                             const int* __restrict__ rowptr,
                                                             const int* __restrict__ col,
                                                             const float* __restrict__ ew,
                                                             const float* __restrict__ dinv,
                                                             const float* __restrict__ bmu,
                                                             const float* __restrict__ bls,
                                                             float4* __restrict__ out4,
                                                             int N) {
    int v = blockIdx.x * 8 + (threadIdx.x >> 5);
    int c = threadIdx.x & 31;
    if (v >= N) return;
    int half = c >> 4, cc = c & 15;
    int beg = rowptr[v], end = rowptr[v + 1];
    float di = dinv[v];
    float4 bb = half ? ((const float4*)bls)[cc] : ((const float4*)bmu)[cc];
    float4 acc0 = f4_fma(t4[(size_t)v * 32 + c], di * di, bb);
    float4 acc1 = make_float4(0.f, 0.f, 0.f, 0.f);
    int e = beg;
    for (; e + 1 < end; e += 2) {
        int s0 = col[e], s1 = col[e + 1];
        float w0 = ew[e], w1 = ew[e + 1];
        float4 a = t4[(size_t)s0 * 32 + c];
        float4 b2 = t4[(size_t)s1 * 32 + c];
        acc0 = f4_fma(a, w0, acc0);
        acc1 = f4_fma(b2, w1, acc1);
    }
    if (e < end) acc0 = f4_fma(t4[(size_t)col[e] * 32 + c], ew[e], acc0);
    out4[(size_t)half * N * 16 + (size_t)v * 16 + cc] = f4_add(acc0, acc1);
}

// ---------------- fallback (atomic scatter) kernels ----------------
__global__ __launch_bounds__(256) void deg_init_kernel(float* deg, int N) {
    int i = blockIdx.x * blockDim.x + threadIdx.x;
    if (i < N) deg[i] = 1.0f;
}
__global__ __launch_bounds__(256) void deg_count_kernel(const int* __restrict__ dst, float* deg, int E) {
    int i = blockIdx.x * blockDim.x + threadIdx.x;
    if (i < E) unsafeAtomicAdd(&deg[dst[i]], 1.0f);
}
__global__ __launch_bounds__(256) void deg_rsqrt_kernel(float* deg, int N) {
    int i = blockIdx.x * blockDim.x + threadIdx.x;
    if (i < N) deg[i] = rsqrtf(deg[i]);
}
__global__ __launch_bounds__(256) void gemm128_kernel(const float* __restrict__ h,
                                                      const float* __restrict__ Wa,
                                                      const float* __restrict__ Wb,
                                                      float* __restrict__ t,
                                                      int N, int relu) {
    __shared__ float Wl[128 * 128];
    __shared__ float hl[2][128];
    for (int i = threadIdx.x; i < 128 * 128; i += 256) {
        int k = i >> 7, j = i & 127;
        float w;
        if (Wb) w = (j < 64) ? Wa[k * 64 + j] : Wb[k * 64 + (j - 64)];
        else    w = Wa[i];
        Wl[i] = w;
    }
    __syncthreads();
    int col = threadIdx.x & 127;
    int r   = threadIdx.x >> 7;
    for (long long pair = blockIdx.x; pair * 2 < N; pair += gridDim.x) {
        int row0 = (int)(pair * 2);
        {
            int rr = threadIdx.x >> 7, k = threadIdx.x & 127;
            int row = row0 + rr;
            float v = (row < N) ? h[(size_t)row * 128 + k] : 0.0f;
            if (relu) v = fmaxf(v, 0.0f);
            hl[rr][k] = v;
        }
        __syncthreads();
        float acc = 0.0f;
        #pragma unroll
        for (int k = 0; k < 128; k += 4) {
            float4 hv = *(const float4*)&hl[r][k];
            acc += hv.x * Wl[(k + 0) * 128 + col];
            acc += hv.y * Wl[(k + 1) * 128 + col];
            acc += hv.z * Wl[(k + 2) * 128 + col];
            acc += hv.w * Wl[(k + 3) * 128 + col];
        }
        int row = row0 + r;
        if (row < N) t[(size_t)row * 128 + col] = acc;
        __syncthreads();
    }
}
__global__ __launch_bounds__(256) void init_self_kernel(const float4* __restrict__ t4,
                                                        const float* __restrict__ dinv,
                                                        const float* __restrict__ b,
                                                        float4* __restrict__ out, int N) {
    int idx = blockIdx.x * blockDim.x + threadIdx.x;
    int v = idx >> 5, c = idx & 31;
    if (v >= N) return;
    float di = dinv[v];
    float s = di * di;
    float4 x = t4[(size_t)v * 32 + c];
    float4 bb = ((const float4*)b)[c];
    out[(size_t)v * 32 + c] = make_float4(fmaf(x.x, s, bb.x), fmaf(x.y, s, bb.y),
                                          fmaf(x.z, s, bb.z), fmaf(x.w, s, bb.w));
}
__global__ __launch_bounds__(256) void init_final_kernel(const float4* __restrict__ t4,
                                                         const float* __restrict__ dinv,
                                                         const float* __restrict__ bmu,
                                                         const float* __restrict__ bls,
                                                         float4* __restrict__ out4, int N) {
    int idx = blockIdx.x * blockDim.x + threadIdx.x;
    int v = idx >> 5, c = idx & 31;
    if (v >= N) return;
    int half = c >> 4, cc = c & 15;
    float di = dinv[v];
    float s = di * di;
    float4 x = t4[(size_t)v * 32 + c];
    float4 bb = half ? ((const float4*)bls)[cc] : ((const float4*)bmu)[cc];
    out4[(size_t)half * N * 16 + (size_t)v * 16 + cc] =
        make_float4(fmaf(x.x, s, bb.x), fmaf(x.y, s, bb.y),
                    fmaf(x.z, s, bb.z), fmaf(x.w, s, bb.w));
}
__global__ __launch_bounds__(256) void agg_edge_kernel(const float4* __restrict__ t4,
                                                       const int* __restrict__ src,
                                                       const int* __restrict__ dst,
                                                       const float* __restrict__ dinv,
                                                       float* __restrict__ out, int E) {
    int idx = blockIdx.x * blockDim.x + threadIdx.x;
    int e = idx >> 5, c = idx & 31;
    if (e >= E) return;
    int s = src[e], d = dst[e];
    float w = dinv[s] * dinv[d];
    float4 v = t4[(size_t)s * 32 + c];
    float* o = out + (size_t)d * 128 + c * 4;
    unsafeAtomicAdd(o + 0, v.x * w);
    unsafeAtomicAdd(o + 1, v.y * w);
    unsafeAtomicAdd(o + 2, v.z * w);
    unsafeAtomicAdd(o + 3, v.w * w);
}
__global__ __launch_bounds__(256) void agg_edge_final_kernel(const float4* __restrict__ t4,
                                                             const int* __restrict__ src,
                                                             const int* __restrict__ dst,
                                                             const float* __restrict__ dinv,
                                                             float* __restrict__ out, int N, int E) {
    int idx = blockIdx.x * blockDim.x + threadIdx.x;
    int e = idx >> 5, c = idx & 31;
    if (e >= E) return;
    int s = src[e], d = dst[e];
    int half = c >> 4, cc = c & 15;
    float w = dinv[s] * dinv[d];
    float4 v = t4[(size_t)s * 32 + c];
    float* o = out + (size_t)half * N * 64 + (size_t)d * 64 + cc * 4;
    unsafeAtomicAdd(o + 0, v.x * w);
    unsafeAtomicAdd(o + 1, v.y * w);
    unsafeAtomicAdd(o + 2, v.z * w);
    unsafeAtomicAdd(o + 3, v.w * w);
}

// ---------------- launch ----------------
extern "C" void kernel_launch(void* const* d_in, const int* in_sizes, int n_in,
                              void* d_out, int out_size, void* d_ws, size_t ws_size,
                              hipStream_t stream) {
    const float* x   = (const float*)d_in[0];
    const int*   ei  = (const int*)d_in[1];
    const float* W1  = (const float*)d_in[2];
    const float* b1  = (const float*)d_in[3];
    const float* W2  = (const float*)d_in[4];
    const float* b2  = (const float*)d_in[5];
    const float* Wmu = (const float*)d_in[6];
    const float* bmu = (const float*)d_in[7];
    const float* Wls = (const float*)d_in[8];
    const float* bls = (const float*)d_in[9];

    const int N = in_sizes[0] / 128;
    const int E = in_sizes[1] / 2;
    const int* src = ei;
    const int* dst = ei + E;

    float* out = (float*)d_out;  // reused as h1/h2 buffer

    auto align256 = [](size_t o) { return (o + 255) & ~(size_t)255; };
    const int B1 = (N + SCAN_CHUNK - 1) / SCAN_CHUNK;

    size_t off = 0;
    size_t o_dinv   = off; off = align256(off + (size_t)N * 4);
    size_t o_t      = off; off = align256(off + (size_t)N * 128 * 4);
    size_t o_rowptr = off; off = align256(off + (size_t)(N + 1) * 4);
    size_t o_cursor = off; off = align256(off + (size_t)N * 4);       // also cnt
    size_t o_bsum   = off; off = align256(off + (size_t)B1 * 4);
    size_t o_col    = off; off = align256(off + (size_t)E * 4);
    size_t o_ew     = off; off = align256(off + (size_t)E * 4);
    size_t need = off;

    float* dinv = (float*)((char*)d_ws + o_dinv);
    float* t    = (float*)((char*)d_ws + o_t);

    const int TB = 256;
    int gN = (N + TB - 1) / TB;
    int gE = (E + TB - 1) / TB;
    int ntiles = (N + TILE_R - 1) / TILE_R;

    if (ws_size >= need) {
        int* rowptr = (int*)((char*)d_ws + o_rowptr);
        int* cursor = (int*)((char*)d_ws + o_cursor);
        int* bsum   = (int*)((char*)d_ws + o_bsum);
        int* col    = (int*)((char*)d_ws + o_col);
        float* ew   = (float*)((char*)d_ws + o_ew);

        // CSR build
        hipMemsetAsync(cursor, 0, (size_t)N * 4, stream);
        cnt_count_kernel<<<gE, TB, 0, stream>>>(dst, cursor, E);
        dinv_kernel<<<gN, TB, 0, stream>>>(cursor, dinv, N);
        scan_reduce_kernel<<<B1, TB, 0, stream>>>(cursor, bsum, N);
        scan_bsum_kernel<<<1, 64, 0, stream>>>(bsum, B1);
        scan_write_kernel<<<B1, TB, 0, stream>>>(cursor, bsum, rowptr, N);
        cursor_init_kernel<<<(N + TB) / TB, TB, 0, stream>>>(rowptr, cursor, rowptr + N, N, E);
        csr_fill_kernel<<<gE, TB, 0, stream>>>(src, dst, dinv, cursor, col, ew, E);

        int gPull = (N + 7) / 8;
        // layer 1 (x not relu'd; hidden aggs write relu directly)
        gemm128_tiled<<<256, TB, 0, stream>>>(x, W1, nullptr, t, N, ntiles);
        agg_pull_kernel<<<gPull, TB, 0, stream>>>((const float4*)t, rowptr, col, ew, dinv, b1, (float4*)out, N, 1);
        // layer 2
        gemm128_tiled<<<256, TB, 0, stream>>>(out, W2, nullptr, t, N, ntiles);
        agg_pull_kernel<<<gPull, TB, 0, stream>>>((const float4*)t, rowptr, col, ew, dinv, b2, (float4*)out, N, 1);
        // layer 3+4 fused
        gemm128_tiled<<<256, TB, 0, stream>>>(out, Wmu, Wls, t, N, ntiles);
        agg_pull_final_kernel<<<gPull, TB, 0, stream>>>((const float4*)t, rowptr, col, ew, dinv, bmu, bls, (float4*)out, N);
    } else {
        // fallback: atomic scatter path
        int gN32  = (N * 32 + TB - 1) / TB;
        int gE32h = (int)(((long long)E * 32 + TB - 1) / TB);
        deg_init_kernel<<<gN, TB, 0, stream>>>(dinv, N);
        deg_count_kernel<<<gE, TB, 0, stream>>>(dst, dinv, E);
        deg_rsqrt_kernel<<<gN, TB, 0, stream>>>(dinv, N);

        gemm128_kernel<<<2048, TB, 0, stream>>>(x, W1, nullptr, t, N, 0);
        init_self_kernel<<<gN32, TB, 0, stream>>>((const float4*)t, dinv, b1, (float4*)out, N);
        agg_edge_kernel<<<gE32h, TB, 0, stream>>>((const float4*)t, src, dst, dinv, out, E);

        gemm128_kernel<<<2048, TB, 0, stream>>>(out, W2, nullptr, t, N, 1);
        init_self_kernel<<<gN32, TB, 0, stream>>>((const float4*)t, dinv, b2, (float4*)out, N);
        agg_edge_kernel<<<gE32h, TB, 0, stream>>>((const float4*)t, src, dst, dinv, out, E);

        gemm128_kernel<<<2048, TB, 0, stream>>>(out, Wmu, Wls, t, N, 1);
        init_final_kernel<<<gN32, TB, 0, stream>>>((const float4*)t, dinv, bmu, bls, (float4*)out, N);
        agg_edge_final_kernel<<<gE32h, TB, 0, stream>>>((const float4*)t, src, dst, dinv, out, N, E);
    }
}